// Round 1
// baseline (72.276 us; speedup 1.0000x reference)
//
#include <hip/hip_runtime.h>

// DifferentiableHistogram: x (4,3,256,256) fp32, bin_centers (512,3) fp32
// (separable 8x8x8 grid), out (4,512) fp32.
//
// Weight factorizes: exp(-||p-c_ijk||^2 * 1250) = ex_i * ey_j * ez_k.
// Per-pixel denom = (sum ex)(sum ey)(sum ez). Histogram = sum over pixels of
// normalized outer product; final per-batch L1 normalize.

#define NPIX   65536      // 256*256
#define NB     4
#define TILE   256        // pixels staged per LDS tile (one per thread)
#define BPB    128        // blocks per batch
#define PPB    (NPIX / BPB)  // 512 pixels per block
#define LDSTR  12         // LDS row stride in floats: 48B, 16B-aligned rows

__global__ __launch_bounds__(256) void hist_accum(
    const float* __restrict__ x, const float* __restrict__ bc,
    float* __restrict__ out)
{
    __shared__ float s_ex[TILE][LDSTR];   // ex[i] * invS
    __shared__ float s_ey[TILE][LDSTR];
    __shared__ float s_ez[TILE][LDSTR];
    __shared__ float s_red[4][512];       // team partials, packed q=(j*8+k)*8+i

    const int tid   = threadIdx.x;
    const int b     = blockIdx.x >> 7;          // BPB == 128
    const int chunk = blockIdx.x & (BPB - 1);
    const int pix0  = chunk * PPB;

    // bin center coords per dim: idx = i*64 + j*8 + k, row = (c_i, c_j, c_k)
    float cx[8], cy[8], cz[8];
#pragma unroll
    for (int i = 0; i < 8; ++i) {
        cx[i] = bc[i * 192 + 0];   // (i*64)*3
        cy[i] = bc[i * 24 + 1];    // (i*8)*3 + 1
        cz[i] = bc[i * 3 + 2];
    }

    const float* xb = x + (size_t)b * 3 * NPIX;
    const int team = tid >> 6;     // 4 teams == 4 waves
    const int lane = tid & 63;
    const int jj   = lane >> 3;
    const int kk   = lane & 7;

    float acc[8];
#pragma unroll
    for (int i = 0; i < 8; ++i) acc[i] = 0.f;

    for (int t = 0; t < PPB / TILE; ++t) {
        // ---- stage: one pixel per thread ----
        const int p = pix0 + t * TILE + tid;
        const float r  = xb[p];
        const float g  = xb[NPIX + p];
        const float bl = xb[2 * NPIX + p];
        float ex[8], ey[8], ez[8];
        float sx = 0.f, sy = 0.f, sz = 0.f;
#pragma unroll
        for (int i = 0; i < 8; ++i) {
            float dx = r  - cx[i]; ex[i] = __expf(dx * dx * -1250.0f); sx += ex[i];
            float dy = g  - cy[i]; ey[i] = __expf(dy * dy * -1250.0f); sy += ey[i];
            float dz = bl - cz[i]; ez[i] = __expf(dz * dz * -1250.0f); sz += ez[i];
        }
        const float invS = 1.0f / (sx * sy * sz + 1e-8f);
#pragma unroll
        for (int i = 0; i < 8; ++i) {
            s_ex[tid][i] = ex[i] * invS;
            s_ey[tid][i] = ey[i];
            s_ez[tid][i] = ez[i];
        }
        __syncthreads();

        // ---- accumulate: team sweeps its 64 pixels; lane owns (jj,kk,i=0..7)
        const int pbase = team * 64;
        for (int q = 0; q < 64; ++q) {
            const int pp = pbase + q;
            const float eyz = s_ey[pp][jj] * s_ez[pp][kk];
#pragma unroll
            for (int i = 0; i < 8; ++i)
                acc[i] += s_ex[pp][i] * eyz;   // s_ex reads: b128 broadcast
        }
        __syncthreads();
    }

    // ---- reduce 4 teams -> block histogram -> global atomic ----
#pragma unroll
    for (int i = 0; i < 8; ++i) s_red[team][lane * 8 + i] = acc[i];
    __syncthreads();

    for (int q = tid; q < 512; q += 256) {
        const float v = s_red[0][q] + s_red[1][q] + s_red[2][q] + s_red[3][q];
        const int bin = ((q & 7) << 6) + (q >> 3);   // i*64 + (j*8+k)
        unsafeAtomicAdd(&out[b * 512 + bin], v);
    }
}

// In-place L1 normalize per batch: out[b,:] /= (sum(out[b,:]) + 1e-8)
__global__ __launch_bounds__(512) void hist_norm(float* __restrict__ out)
{
    const int b = blockIdx.x;
    const int t = threadIdx.x;
    const float v = out[b * 512 + t];
    float s = v;
#pragma unroll
    for (int off = 32; off > 0; off >>= 1) s += __shfl_down(s, off, 64);
    __shared__ float red[8];
    if ((t & 63) == 0) red[t >> 6] = s;
    __syncthreads();
    float S = 0.f;
#pragma unroll
    for (int i = 0; i < 8; ++i) S += red[i];
    out[b * 512 + t] = v / (S + 1e-8f);
}

extern "C" void kernel_launch(void* const* d_in, const int* in_sizes, int n_in,
                              void* d_out, int out_size, void* d_ws, size_t ws_size,
                              hipStream_t stream) {
    const float* x  = (const float*)d_in[0];
    const float* bc = (const float*)d_in[1];
    float* out = (float*)d_out;

    // d_out is poisoned 0xAA before every launch; zero it (capturable async op)
    hipMemsetAsync(out, 0, (size_t)out_size * sizeof(float), stream);

    hist_accum<<<dim3(NB * BPB), dim3(256), 0, stream>>>(x, bc, out);
    hist_norm<<<dim3(NB), dim3(512), 0, stream>>>(out);
}